// Round 1
// baseline (2545.102 us; speedup 1.0000x reference)
//
#include <hip/hip_runtime.h>
#include <cstdint>

typedef unsigned short u16;
typedef __attribute__((ext_vector_type(8))) short short8;
typedef __attribute__((ext_vector_type(4))) short short4v;
typedef __attribute__((ext_vector_type(4))) float floatx4;

__device__ __forceinline__ u16 f2bf(float f) {
    unsigned u = __float_as_uint(f);
    return (u16)((u + 0x7FFFu + ((u >> 16) & 1u)) >> 16);  // RNE
}
__device__ __forceinline__ float bf2f(u16 h) {
    return __uint_as_float(((unsigned)h) << 16);
}

// async global -> LDS, 16B per lane. LDS dest is wave-uniform base + lane*16.
__device__ __forceinline__ void gload16(u16* lds, const u16* g) {
    __builtin_amdgcn_global_load_lds(
        (const __attribute__((address_space(1))) unsigned*)g,
        (__attribute__((address_space(3))) unsigned*)lds,
        16, 0, 0);
}

// ---------------- elementwise f32 -> bf16 cast (vectorized) ----------------
__global__ void cast_kernel(const float* __restrict__ in, u16* __restrict__ out, int n4) {
    int stride = gridDim.x * blockDim.x;
    for (int i = blockIdx.x * blockDim.x + threadIdx.x; i < n4; i += stride) {
        float4 v = ((const float4*)in)[i];
        short4v o;
        o[0] = (short)f2bf(v.x);
        o[1] = (short)f2bf(v.y);
        o[2] = (short)f2bf(v.z);
        o[3] = (short)f2bf(v.w);
        ((short4v*)out)[i] = o;
    }
}

// ------------- emb [32000][4096] f32 -> Et [4096][32000] bf16 --------------
__global__ void transpose_cast(const float* __restrict__ E, u16* __restrict__ Et) {
    __shared__ u16 t[32][34];  // pad: 17-word row stride, conflict-free
    int bx = blockIdx.x, by = blockIdx.y;
    int x = threadIdx.x, y = threadIdx.y;
    long long c = (long long)bx * 32 + x;   // d index (0..4095)
    long long r0 = (long long)by * 32;      // v base  (0..31999)
#pragma unroll
    for (int i = y; i < 32; i += 8)
        t[x][i] = f2bf(E[(r0 + i) * 4096 + c]);
    __syncthreads();
    int v = by * 32 + x;
#pragma unroll
    for (int i = y; i < 32; i += 8)
        Et[(long long)(bx * 32 + i) * 32000 + v] = t[i][x];
}

// ---------------- row sums of P (bf16) -> l (f32), deterministic -----------
__global__ void rowsum_kernel(const u16* __restrict__ P, float* __restrict__ l, int V) {
    long long base = (long long)blockIdx.x * V;
    const short8* p8 = (const short8*)(P + base);
    int n8 = V >> 3;
    float s = 0.f;
    for (int c = threadIdx.x; c < n8; c += blockDim.x) {
        short8 v = p8[c];
#pragma unroll
        for (int j = 0; j < 8; ++j) s += bf2f((u16)v[j]);
    }
#pragma unroll
    for (int off = 32; off > 0; off >>= 1) s += __shfl_down(s, off, 64);
    __shared__ float red[4];
    if ((threadIdx.x & 63) == 0) red[threadIdx.x >> 6] = s;
    __syncthreads();
    if (threadIdx.x == 0) l[blockIdx.x] = red[0] + red[1] + red[2] + red[3];
}

// ---------------- NT GEMM: C[M][N] = A[M][K] * B[N][K]^T -------------------
// 128x128 tile, BK=32, 4 waves (2x2, 64x64 each), 16x16x32 bf16 MFMA.
// EP=0: C -> exp(C + bias[col]) stored bf16 (P).  EP=1: C/rowsum[row] -> f32.
template <int EP>
__global__ __launch_bounds__(256)
void gemm_nt(const u16* __restrict__ A, const u16* __restrict__ B,
             int M, int N, int K,
             const float* __restrict__ bias, u16* __restrict__ Pout,
             const float* __restrict__ rsum, float* __restrict__ Cout) {
    __shared__ u16 sA[128 * 32];
    __shared__ u16 sB[128 * 32];
    const int tid = threadIdx.x;
    const int wave = tid >> 6, lane = tid & 63;

    // band-of-8 tile mapping: consecutive blocks sweep 8 tm rows, then tn.
    const int nTn = N >> 7;
    const int bandSz = nTn << 3;
    const int band = blockIdx.x / bandSz;
    const int rem = blockIdx.x % bandSz;
    const int tn = rem >> 3;
    const int tm = (band << 3) + (rem & 7);

    const u16* Abase = A + (long long)tm * 128 * K;
    const u16* Bbase = B + (long long)tn * 128 * K;

    // staging: per wave, 16 consecutive rows per chunk; lane covers 16B each
    const int sRow = lane >> 2;          // 0..15
    const int sCol = (lane & 3) * 8;     // elem offset in BK=32
    const u16* aSrc0 = Abase + (long long)(wave * 16 + sRow) * K + sCol;
    const u16* aSrc1 = aSrc0 + (long long)64 * K;
    const u16* bSrc0 = Bbase + (long long)(wave * 16 + sRow) * K + sCol;
    const u16* bSrc1 = bSrc0 + (long long)64 * K;
    u16* ldsA0 = &sA[(wave * 16) * 32];
    u16* ldsA1 = &sA[(64 + wave * 16) * 32];
    u16* ldsB0 = &sB[(wave * 16) * 32];
    u16* ldsB1 = &sB[(64 + wave * 16) * 32];

    const int wm = wave >> 1, wn = wave & 1;
    const int fRow = lane & 15;
    const int fK = (lane >> 4) * 8;      // k-chunk within BK

    floatx4 acc[4][4] = {};

    for (int kt = 0; kt < K; kt += 32) {
        gload16(ldsA0, aSrc0 + kt);
        gload16(ldsA1, aSrc1 + kt);
        gload16(ldsB0, bSrc0 + kt);
        gload16(ldsB1, bSrc1 + kt);
        __syncthreads();  // drains vmcnt before barrier

        short8 af[4], bfv[4];
#pragma unroll
        for (int m = 0; m < 4; ++m)
            af[m] = *(const short8*)&sA[(wm * 64 + m * 16 + fRow) * 32 + fK];
#pragma unroll
        for (int n = 0; n < 4; ++n)
            bfv[n] = *(const short8*)&sB[(wn * 64 + n * 16 + fRow) * 32 + fK];
#pragma unroll
        for (int m = 0; m < 4; ++m)
#pragma unroll
            for (int n = 0; n < 4; ++n)
                acc[m][n] = __builtin_amdgcn_mfma_f32_16x16x32_bf16(
                    af[m], bfv[n], acc[m][n], 0, 0, 0);
        __syncthreads();
    }

    // epilogue: C/D layout col=lane&15, row=(lane>>4)*4+reg (m89-verified)
    const int rBase = tm * 128 + wm * 64;
    const int cBase = tn * 128 + wn * 64;
    const int rOff = (lane >> 4) * 4;
    const int cOff = lane & 15;
#pragma unroll
    for (int m = 0; m < 4; ++m) {
#pragma unroll
        for (int n = 0; n < 4; ++n) {
            const int col = cBase + n * 16 + cOff;
            if (EP == 0) {
                float bv = bias[col];
#pragma unroll
                for (int r = 0; r < 4; ++r) {
                    int row = rBase + m * 16 + rOff + r;
                    Pout[(long long)row * N + col] = f2bf(__expf(acc[m][n][r] + bv));
                }
            } else {
#pragma unroll
                for (int r = 0; r < 4; ++r) {
                    int row = rBase + m * 16 + rOff + r;
                    Cout[(long long)row * N + col] = acc[m][n][r] * (1.0f / rsum[row]);
                }
            }
        }
    }
}

extern "C" void kernel_launch(void* const* d_in, const int* in_sizes, int n_in,
                              void* d_out, int out_size, void* d_ws, size_t ws_size,
                              hipStream_t stream) {
    const float* x = (const float*)d_in[0];   // [2,2048,1024]
    const float* W = (const float*)d_in[1];   // [32000,1024]
    const float* b = (const float*)d_in[2];   // [32000]
    const float* E = (const float*)d_in[3];   // [32000,4096]
    float* out = (float*)d_out;               // [2,2048,4096]

    const int M = 4096, K1 = 1024, V = 32000, N2 = 4096;

    char* ws = (char*)d_ws;
    size_t off = 0;
    u16* xb = (u16*)(ws + off); off += (size_t)M * K1 * 2;   //   8.4 MB
    u16* Wb = (u16*)(ws + off); off += (size_t)V * K1 * 2;   //  65.5 MB
    u16* Et = (u16*)(ws + off); off += (size_t)N2 * V * 2;   // 262.1 MB
    u16* P  = (u16*)(ws + off); off += (size_t)M * V * 2;    // 262.1 MB
    float* l = (float*)(ws + off); off += (size_t)M * 4;     // ~598 MB total

    cast_kernel<<<2048, 256, 0, stream>>>(x, xb, M * K1 / 4);
    cast_kernel<<<2048, 256, 0, stream>>>(W, Wb, V * K1 / 4);
    transpose_cast<<<dim3(N2 / 32, V / 32), dim3(32, 8), 0, stream>>>(E, Et);
    gemm_nt<0><<<(M / 128) * (V / 128), 256, 0, stream>>>(xb, Wb, M, V, K1, b, P, nullptr, nullptr);
    rowsum_kernel<<<M, 256, 0, stream>>>(P, l, V);
    gemm_nt<1><<<(M / 128) * (N2 / 128), 256, 0, stream>>>(P, Et, M, N2, V, nullptr, nullptr, l, out);
}

// Round 2
// 2529.190 us; speedup vs baseline: 1.0063x; 1.0063x over previous
//
#include <hip/hip_runtime.h>
#include <cstdint>

typedef unsigned short u16;
typedef __attribute__((ext_vector_type(8))) short short8;
typedef __attribute__((ext_vector_type(4))) short short4v;
typedef __attribute__((ext_vector_type(4))) float floatx4;

__device__ __forceinline__ u16 f2bf(float f) {
    unsigned u = __float_as_uint(f);
    return (u16)((u + 0x7FFFu + ((u >> 16) & 1u)) >> 16);  // RNE
}
__device__ __forceinline__ float bf2f(u16 h) {
    return __uint_as_float(((unsigned)h) << 16);
}

// async global -> LDS, 16B per lane. LDS dest is wave-uniform base + lane*16.
__device__ __forceinline__ void gload16(u16* lds, const u16* g) {
    __builtin_amdgcn_global_load_lds(
        (const __attribute__((address_space(1))) unsigned*)g,
        (__attribute__((address_space(3))) unsigned*)lds,
        16, 0, 0);
}

// ---------------- elementwise f32 -> bf16 cast (vectorized) ----------------
__global__ void cast_kernel(const float* __restrict__ in, u16* __restrict__ out, int n4) {
    int stride = gridDim.x * blockDim.x;
    for (int i = blockIdx.x * blockDim.x + threadIdx.x; i < n4; i += stride) {
        float4 v = ((const float4*)in)[i];
        short4v o;
        o[0] = (short)f2bf(v.x);
        o[1] = (short)f2bf(v.y);
        o[2] = (short)f2bf(v.z);
        o[3] = (short)f2bf(v.w);
        ((short4v*)out)[i] = o;
    }
}

// ------------- emb [32000][4096] f32 -> Et [4096][32000] bf16 --------------
__global__ void transpose_cast(const float* __restrict__ E, u16* __restrict__ Et) {
    __shared__ u16 t[32][34];  // pad: conflict-free
    int bx = blockIdx.x, by = blockIdx.y;
    int x = threadIdx.x, y = threadIdx.y;
    long long c = (long long)bx * 32 + x;   // d index (0..4095)
    long long r0 = (long long)by * 32;      // v base  (0..31999)
#pragma unroll
    for (int i = y; i < 32; i += 8)
        t[x][i] = f2bf(E[(r0 + i) * 4096 + c]);
    __syncthreads();
    int v = by * 32 + x;
#pragma unroll
    for (int i = y; i < 32; i += 8)
        Et[(long long)(bx * 32 + i) * 32000 + v] = t[i][x];
}

// ---------------- row sums of P (bf16) -> l (f32), deterministic -----------
__global__ void rowsum_kernel(const u16* __restrict__ P, float* __restrict__ l, int V) {
    long long base = (long long)blockIdx.x * V;
    const short8* p8 = (const short8*)(P + base);
    int n8 = V >> 3;
    float s = 0.f;
    for (int c = threadIdx.x; c < n8; c += blockDim.x) {
        short8 v = p8[c];
#pragma unroll
        for (int j = 0; j < 8; ++j) s += bf2f((u16)v[j]);
    }
#pragma unroll
    for (int off = 32; off > 0; off >>= 1) s += __shfl_down(s, off, 64);
    __shared__ float red[4];
    if ((threadIdx.x & 63) == 0) red[threadIdx.x >> 6] = s;
    __syncthreads();
    if (threadIdx.x == 0) l[blockIdx.x] = red[0] + red[1] + red[2] + red[3];
}

// ---------------- NT GEMM: C[M][N] = A[M][K] * B[N][K]^T -------------------
// 128x128 tile, BK=32, 4 waves (2x2, 64x64 each), 16x16x32 bf16 MFMA.
// LDS tile [128][32] bf16 (64B rows), XOR-swizzled chunk slots:
//   global chunk c of row r lives in 16B slot (c ^ ((r>>1)&3)).
// Swizzle applied on the SOURCE side of global_load_lds (rule #21) and on
// the ds_read address; rows 0-7 then span all 8 bank-groups (2 lanes/bank,
// free per m136) instead of 8-way conflicts.
// EP=0: C -> exp(C + bias[col]) stored bf16 (P).  EP=1: C/rowsum[row] -> f32.
template <int EP>
__global__ __launch_bounds__(256)
void gemm_nt(const u16* __restrict__ A, const u16* __restrict__ B,
             int M, int N, int K,
             const float* __restrict__ bias, u16* __restrict__ Pout,
             const float* __restrict__ rsum, float* __restrict__ Cout) {
    __shared__ u16 sA[128 * 32];
    __shared__ u16 sB[128 * 32];
    const int tid = threadIdx.x;
    const int wave = tid >> 6, lane = tid & 63;

    // band-of-8 tile mapping: consecutive blocks sweep 8 tm rows, then tn.
    const int nTn = N >> 7;
    const int bandSz = nTn << 3;
    const int band = blockIdx.x / bandSz;
    const int rem = blockIdx.x % bandSz;
    const int tn = rem >> 3;
    const int tm = (band << 3) + (rem & 7);

    const u16* Abase = A + (long long)tm * 128 * K;
    const u16* Bbase = B + (long long)tn * 128 * K;

    // staging: per wave, 16 consecutive rows per chunk; lane covers 16B each.
    // source chunk is pre-swizzled so linear LDS ends up XOR-swizzled.
    const int sRow = lane >> 2;                       // 0..15
    const int gChunk = (lane & 3) ^ ((sRow >> 1) & 3);
    const int sCol = gChunk * 8;                      // elem offset in BK=32
    const u16* aSrc0 = Abase + (long long)(wave * 16 + sRow) * K + sCol;
    const u16* aSrc1 = aSrc0 + (long long)64 * K;
    const u16* bSrc0 = Bbase + (long long)(wave * 16 + sRow) * K + sCol;
    const u16* bSrc1 = bSrc0 + (long long)64 * K;
    u16* ldsA0 = &sA[(wave * 16) * 32];
    u16* ldsA1 = &sA[(64 + wave * 16) * 32];
    u16* ldsB0 = &sB[(wave * 16) * 32];
    u16* ldsB1 = &sB[(64 + wave * 16) * 32];

    const int wm = wave >> 1, wn = wave & 1;
    const int fRow = lane & 15;
    const int fC = lane >> 4;                         // k-chunk 0..3
    const int slot = fC ^ ((fRow >> 1) & 3);          // swizzled 16B slot
    const int rdOff = slot * 8;                       // elem offset

    floatx4 acc[4][4] = {};

    for (int kt = 0; kt < K; kt += 32) {
        gload16(ldsA0, aSrc0 + kt);
        gload16(ldsA1, aSrc1 + kt);
        gload16(ldsB0, bSrc0 + kt);
        gload16(ldsB1, bSrc1 + kt);
        __syncthreads();  // drains vmcnt before barrier

        short8 af[4], bfv[4];
#pragma unroll
        for (int m = 0; m < 4; ++m)
            af[m] = *(const short8*)&sA[(wm * 64 + m * 16 + fRow) * 32 + rdOff];
#pragma unroll
        for (int n = 0; n < 4; ++n)
            bfv[n] = *(const short8*)&sB[(wn * 64 + n * 16 + fRow) * 32 + rdOff];
#pragma unroll
        for (int m = 0; m < 4; ++m)
#pragma unroll
            for (int n = 0; n < 4; ++n)
                acc[m][n] = __builtin_amdgcn_mfma_f32_16x16x32_bf16(
                    af[m], bfv[n], acc[m][n], 0, 0, 0);
        __syncthreads();
    }

    // epilogue: C/D layout col=lane&15, row=(lane>>4)*4+reg (m89-verified)
    const int rBase = tm * 128 + wm * 64;
    const int cBase = tn * 128 + wn * 64;
    const int rOff = (lane >> 4) * 4;
    const int cOff = lane & 15;
#pragma unroll
    for (int m = 0; m < 4; ++m) {
#pragma unroll
        for (int n = 0; n < 4; ++n) {
            const int col = cBase + n * 16 + cOff;
            if (EP == 0) {
                float bv = bias[col];
#pragma unroll
                for (int r = 0; r < 4; ++r) {
                    int row = rBase + m * 16 + rOff + r;
                    Pout[(long long)row * N + col] = f2bf(__expf(acc[m][n][r] + bv));
                }
            } else {
#pragma unroll
                for (int r = 0; r < 4; ++r) {
                    int row = rBase + m * 16 + rOff + r;
                    Cout[(long long)row * N + col] = acc[m][n][r] * (1.0f / rsum[row]);
                }
            }
        }
    }
}

extern "C" void kernel_launch(void* const* d_in, const int* in_sizes, int n_in,
                              void* d_out, int out_size, void* d_ws, size_t ws_size,
                              hipStream_t stream) {
    const float* x = (const float*)d_in[0];   // [2,2048,1024]
    const float* W = (const float*)d_in[1];   // [32000,1024]
    const float* b = (const float*)d_in[2];   // [32000]
    const float* E = (const float*)d_in[3];   // [32000,4096]
    float* out = (float*)d_out;               // [2,2048,4096]

    const int M = 4096, K1 = 1024, V = 32000, N2 = 4096;

    char* ws = (char*)d_ws;
    size_t off = 0;
    u16* xb = (u16*)(ws + off); off += (size_t)M * K1 * 2;   //   8.4 MB
    u16* Wb = (u16*)(ws + off); off += (size_t)V * K1 * 2;   //  65.5 MB
    u16* Et = (u16*)(ws + off); off += (size_t)N2 * V * 2;   // 262.1 MB
    u16* P  = (u16*)(ws + off); off += (size_t)M * V * 2;    // 262.1 MB
    float* l = (float*)(ws + off); off += (size_t)M * 4;     // ~598 MB total

    cast_kernel<<<2048, 256, 0, stream>>>(x, xb, M * K1 / 4);
    cast_kernel<<<2048, 256, 0, stream>>>(W, Wb, V * K1 / 4);
    transpose_cast<<<dim3(N2 / 32, V / 32), dim3(32, 8), 0, stream>>>(E, Et);
    gemm_nt<0><<<(M / 128) * (V / 128), 256, 0, stream>>>(xb, Wb, M, V, K1, b, P, nullptr, nullptr);
    rowsum_kernel<<<M, 256, 0, stream>>>(P, l, V);
    gemm_nt<1><<<(M / 128) * (N2 / 128), 256, 0, stream>>>(P, Et, M, N2, V, nullptr, nullptr, l, out);
}

// Round 3
// 1442.965 us; speedup vs baseline: 1.7638x; 1.7528x over previous
//
#include <hip/hip_runtime.h>
#include <cstdint>

typedef unsigned short u16;
typedef __attribute__((ext_vector_type(8))) short short8;
typedef __attribute__((ext_vector_type(4))) short short4v;
typedef __attribute__((ext_vector_type(4))) float floatx4;

__device__ __forceinline__ u16 f2bf(float f) {
    unsigned u = __float_as_uint(f);
    return (u16)((u + 0x7FFFu + ((u >> 16) & 1u)) >> 16);  // RNE
}
__device__ __forceinline__ float bf2f(u16 h) {
    return __uint_as_float(((unsigned)h) << 16);
}

__device__ __forceinline__ void gload16(u16* lds, const u16* g) {
    __builtin_amdgcn_global_load_lds(
        (const __attribute__((address_space(1))) unsigned*)g,
        (__attribute__((address_space(3))) unsigned*)lds,
        16, 0, 0);
}

#define CFENCE asm volatile("" ::: "memory")

// ---------------- elementwise f32 -> bf16 cast (vectorized) ----------------
__global__ void cast_kernel(const float* __restrict__ in, u16* __restrict__ out, int n4) {
    int stride = gridDim.x * blockDim.x;
    for (int i = blockIdx.x * blockDim.x + threadIdx.x; i < n4; i += stride) {
        float4 v = ((const float4*)in)[i];
        short4v o;
        o[0] = (short)f2bf(v.x);
        o[1] = (short)f2bf(v.y);
        o[2] = (short)f2bf(v.z);
        o[3] = (short)f2bf(v.w);
        ((short4v*)out)[i] = o;
    }
}

// ------------- emb [32000][4096] f32 -> Et [4096][32000] bf16 --------------
__global__ void transpose_cast(const float* __restrict__ E, u16* __restrict__ Et) {
    __shared__ u16 t[32][34];
    int bx = blockIdx.x, by = blockIdx.y;
    int x = threadIdx.x, y = threadIdx.y;
    long long c = (long long)bx * 32 + x;
    long long r0 = (long long)by * 32;
#pragma unroll
    for (int i = y; i < 32; i += 8)
        t[x][i] = f2bf(E[(r0 + i) * 4096 + c]);
    __syncthreads();
    int v = by * 32 + x;
#pragma unroll
    for (int i = y; i < 32; i += 8)
        Et[(long long)(bx * 32 + i) * 32000 + v] = t[i][x];
}

// ---------------- row sums of P (bf16) -> l (f32), deterministic -----------
__global__ void rowsum_kernel(const u16* __restrict__ P, float* __restrict__ l, int V) {
    long long base = (long long)blockIdx.x * V;
    const short8* p8 = (const short8*)(P + base);
    int n8 = V >> 3;
    float s = 0.f;
    for (int c = threadIdx.x; c < n8; c += blockDim.x) {
        short8 v = p8[c];
#pragma unroll
        for (int j = 0; j < 8; ++j) s += bf2f((u16)v[j]);
    }
#pragma unroll
    for (int off = 32; off > 0; off >>= 1) s += __shfl_down(s, off, 64);
    __shared__ float red[4];
    if ((threadIdx.x & 63) == 0) red[threadIdx.x >> 6] = s;
    __syncthreads();
    if (threadIdx.x == 0) l[blockIdx.x] = red[0] + red[1] + red[2] + red[3];
}

// =================== 256x256 8-phase NT GEMM (T1-T5) =======================
// C[M][N] = A[M][K] * B[N][K]^T. 8 waves (2Mx4N), BK=64, 2 K-tile dbuf.
// LDS [buf][op][half][128][64] bf16 = 128 KiB.
//   A-half h local row r: global row (r>>6)*128 + h*64 + (r&63)
//   B-half h local row r: global row (r>>5)*64  + h*32 + (r&31)
// Swizzle: LDS[r][slot] holds global chunk slot^((r>>1)&7)  (16B chunks).

__device__ __forceinline__ void stageA(u16* ldsh, const u16* Abase, int h, int t,
                                       int K, int w, int lane) {
#pragma unroll
    for (int i = 0; i < 2; ++i) {
        int r = w * 16 + i * 8 + (lane >> 3);
        int gc = (lane & 7) ^ ((r >> 1) & 7);
        int grow = ((r >> 6) << 7) + (h << 6) + (r & 63);
        gload16(ldsh + (w * 16 + i * 8) * 64,
                Abase + (long long)grow * K + t * 64 + gc * 8);
    }
}
__device__ __forceinline__ void stageB(u16* ldsh, const u16* Bbase, int h, int t,
                                       int K, int w, int lane) {
#pragma unroll
    for (int i = 0; i < 2; ++i) {
        int r = w * 16 + i * 8 + (lane >> 3);
        int gc = (lane & 7) ^ ((r >> 1) & 7);
        int grow = ((r >> 5) << 6) + (h << 5) + (r & 31);
        gload16(ldsh + (w * 16 + i * 8) * 64,
                Bbase + (long long)grow * K + t * 64 + gc * 8);
    }
}

template <int MH>
__device__ __forceinline__ void loadA(short8 af[4][2], const u16 (*lA)[128][64],
                                      int wm, int fRow, int fC) {
#pragma unroll
    for (int m = 0; m < 4; ++m)
#pragma unroll
        for (int kk = 0; kk < 2; ++kk) {
            int R = wm * 64 + m * 16 + fRow;
            int slot = (kk * 4 + fC) ^ ((R >> 1) & 7);
            af[m][kk] = *(const short8*)&lA[MH][R][slot * 8];
        }
}
template <int NH>
__device__ __forceinline__ void loadB(short8 bf[2][2], const u16 (*lB)[128][64],
                                      int wn, int fRow, int fC) {
#pragma unroll
    for (int n = 0; n < 2; ++n)
#pragma unroll
        for (int kk = 0; kk < 2; ++kk) {
            int R = wn * 32 + n * 16 + fRow;
            int slot = (kk * 4 + fC) ^ ((R >> 1) & 7);
            bf[n][kk] = *(const short8*)&lB[NH][R][slot * 8];
        }
}
template <int MH, int NH>
__device__ __forceinline__ void mfma16(floatx4 acc[8][4], short8 af[4][2],
                                       short8 bf[2][2]) {
#pragma unroll
    for (int m = 0; m < 4; ++m)
#pragma unroll
        for (int n = 0; n < 2; ++n)
#pragma unroll
            for (int kk = 0; kk < 2; ++kk)
                acc[MH * 4 + m][NH * 2 + n] = __builtin_amdgcn_mfma_f32_16x16x32_bf16(
                    af[m][kk], bf[n][kk], acc[MH * 4 + m][NH * 2 + n], 0, 0, 0);
}

// EP=0: store exp(C + bias[col]) as bf16.  EP=1: store C/rowsum[row] as f32.
template <int EP>
__global__ __launch_bounds__(512, 2)
void gemm8p(const u16* __restrict__ A, const u16* __restrict__ B,
            int M, int N, int K,
            const float* __restrict__ bias, u16* __restrict__ Pout,
            const float* __restrict__ rsum, float* __restrict__ Cout) {
    __shared__ u16 lds[2][2][2][128][64];
    const int tid = threadIdx.x;
    const int w = tid >> 6, lane = tid & 63;
    const int wm = w >> 2, wn = w & 3;
    const int fRow = lane & 15, fC = lane >> 4;

    // T1: XCD-chunked swizzle (grid % 8 == 0), then column-major tile map
    const int nTm = M >> 8;
    const int q = gridDim.x >> 3;
    const int wg = (blockIdx.x & 7) * q + (blockIdx.x >> 3);
    const int tm = wg % nTm, tn = wg / nTm;

    const u16* Abase = A + (long long)tm * 256 * K;
    const u16* Bbase = B + (long long)tn * 256 * K;
    const int NT = K >> 6;

    floatx4 acc[8][4] = {};
    short8 af[4][2], bf[2][2];

    // ---- prologue: tile0 (4 halves) + tile1 {Ah0,Bh1,Ah1} -> vmcnt(6) ----
    stageA(&lds[0][0][0][0][0], Abase, 0, 0, K, w, lane);
    stageB(&lds[0][1][0][0][0], Bbase, 0, 0, K, w, lane);
    stageB(&lds[0][1][1][0][0], Bbase, 1, 0, K, w, lane);
    stageA(&lds[0][0][1][0][0], Abase, 1, 0, K, w, lane);
    if (NT > 1) {
        stageA(&lds[1][0][0][0][0], Abase, 0, 1, K, w, lane);
        stageB(&lds[1][1][1][0][0], Bbase, 1, 1, K, w, lane);
        stageA(&lds[1][0][1][0][0], Abase, 1, 1, K, w, lane);
        asm volatile("s_waitcnt vmcnt(6)" ::: "memory");
    } else {
        asm volatile("s_waitcnt vmcnt(0)" ::: "memory");
    }
    __builtin_amdgcn_s_barrier();
    CFENCE;

    for (int t = 0; t < NT; ++t) {
        const int d = t & 1;
        const u16(*lA)[128][64] = lds[d][0];
        const u16(*lB)[128][64] = lds[d][1];

        // ---- P1: quadrant (0,0); stage Bh0(t+1) ----
        loadA<0>(af, lA, wm, fRow, fC);
        loadB<0>(bf, lB, wn, fRow, fC);
        if (t + 1 < NT) stageB(&lds[d ^ 1][1][0][0][0], Bbase, 0, t + 1, K, w, lane);
        asm volatile("s_waitcnt lgkmcnt(8)" ::: "memory");
        __builtin_amdgcn_s_barrier();
        asm volatile("s_waitcnt lgkmcnt(0)" ::: "memory");
        __builtin_amdgcn_s_setprio(1);
        mfma16<0, 0>(acc, af, bf);
        __builtin_amdgcn_s_setprio(0);
        __builtin_amdgcn_s_barrier();
        CFENCE;

        // ---- P2: quadrant (0,1); stage Ah0(t+2) ----
        loadB<1>(bf, lB, wn, fRow, fC);
        if (t + 2 < NT) stageA(&lds[d][0][0][0][0], Abase, 0, t + 2, K, w, lane);
        __builtin_amdgcn_s_barrier();
        asm volatile("s_waitcnt lgkmcnt(0)" ::: "memory");
        __builtin_amdgcn_s_setprio(1);
        mfma16<0, 1>(acc, af, bf);
        __builtin_amdgcn_s_setprio(0);
        __builtin_amdgcn_s_barrier();
        CFENCE;

        // ---- P3: quadrant (1,1); stage Bh1(t+2) ----
        loadA<1>(af, lA, wm, fRow, fC);
        if (t + 2 < NT) stageB(&lds[d][1][1][0][0], Bbase, 1, t + 2, K, w, lane);
        __builtin_amdgcn_s_barrier();
        asm volatile("s_waitcnt lgkmcnt(0)" ::: "memory");
        __builtin_amdgcn_s_setprio(1);
        mfma16<1, 1>(acc, af, bf);
        __builtin_amdgcn_s_setprio(0);
        __builtin_amdgcn_s_barrier();
        CFENCE;

        // ---- P4: quadrant (1,0); stage Ah1(t+2); counted vmcnt ----
        loadB<0>(bf, lB, wn, fRow, fC);
        if (t + 2 < NT) {
            stageA(&lds[d][0][1][0][0], Abase, 1, t + 2, K, w, lane);
            asm volatile("s_waitcnt vmcnt(6)" ::: "memory");
        } else if (t + 1 < NT) {
            asm volatile("s_waitcnt vmcnt(0)" ::: "memory");
        }
        __builtin_amdgcn_s_barrier();
        asm volatile("s_waitcnt lgkmcnt(0)" ::: "memory");
        __builtin_amdgcn_s_setprio(1);
        mfma16<1, 0>(acc, af, bf);
        __builtin_amdgcn_s_setprio(0);
        __builtin_amdgcn_s_barrier();
        CFENCE;
    }

    // ---- epilogue: C/D layout col=lane&15, row=(lane>>4)*4+reg ----
    const int rBase = tm * 256 + wm * 128;
    const int cBase = tn * 256 + wn * 64;
    const int rOff = (lane >> 4) * 4;
    const int cOff = lane & 15;
#pragma unroll
    for (int m = 0; m < 8; ++m) {
#pragma unroll
        for (int n = 0; n < 4; ++n) {
            const int col = cBase + n * 16 + cOff;
            if (EP == 0) {
                float bv = bias[col];
#pragma unroll
                for (int r = 0; r < 4; ++r) {
                    int row = rBase + m * 16 + rOff + r;
                    Pout[(long long)row * N + col] = f2bf(__expf(acc[m][n][r] + bv));
                }
            } else {
#pragma unroll
                for (int r = 0; r < 4; ++r) {
                    int row = rBase + m * 16 + rOff + r;
                    Cout[(long long)row * N + col] = acc[m][n][r] * (1.0f / rsum[row]);
                }
            }
        }
    }
}

extern "C" void kernel_launch(void* const* d_in, const int* in_sizes, int n_in,
                              void* d_out, int out_size, void* d_ws, size_t ws_size,
                              hipStream_t stream) {
    const float* x = (const float*)d_in[0];   // [2,2048,1024]
    const float* W = (const float*)d_in[1];   // [32000,1024]
    const float* b = (const float*)d_in[2];   // [32000]
    const float* E = (const float*)d_in[3];   // [32000,4096]
    float* out = (float*)d_out;               // [2,2048,4096]

    const int M = 4096, K1 = 1024, V = 32000, N2 = 4096;

    char* ws = (char*)d_ws;
    size_t off = 0;
    u16* xb = (u16*)(ws + off); off += (size_t)M * K1 * 2;
    u16* Wb = (u16*)(ws + off); off += (size_t)V * K1 * 2;
    u16* Et = (u16*)(ws + off); off += (size_t)N2 * V * 2;
    u16* P  = (u16*)(ws + off); off += (size_t)M * V * 2;
    float* l = (float*)(ws + off); off += (size_t)M * 4;

    cast_kernel<<<2048, 256, 0, stream>>>(x, xb, M * K1 / 4);
    cast_kernel<<<2048, 256, 0, stream>>>(W, Wb, V * K1 / 4);
    transpose_cast<<<dim3(N2 / 32, V / 32), dim3(32, 8), 0, stream>>>(E, Et);
    // GEMM1: [4096 x 32000 x 1024] -> P = exp(x@W^T + b), bf16
    gemm8p<0><<<(M / 256) * (V / 256), 512, 0, stream>>>(xb, Wb, M, V, K1, b, P, nullptr, nullptr);
    rowsum_kernel<<<M, 256, 0, stream>>>(P, l, V);
    // GEMM2: [4096 x 4096 x 32000] -> out = (P/l) @ Et^T, f32
    gemm8p<1><<<(M / 256) * (N2 / 256), 512, 0, stream>>>(P, Et, M, N2, V, nullptr, nullptr, l, out);
}

// Round 4
// 1416.288 us; speedup vs baseline: 1.7970x; 1.0188x over previous
//
#include <hip/hip_runtime.h>
#include <cstdint>

typedef unsigned short u16;
typedef __attribute__((ext_vector_type(8))) short short8;
typedef __attribute__((ext_vector_type(4))) short short4v;
typedef __attribute__((ext_vector_type(4))) float floatx4;

__device__ __forceinline__ u16 f2bf(float f) {
    unsigned u = __float_as_uint(f);
    return (u16)((u + 0x7FFFu + ((u >> 16) & 1u)) >> 16);  // RNE
}
__device__ __forceinline__ float bf2f(u16 h) {
    return __uint_as_float(((unsigned)h) << 16);
}

__device__ __forceinline__ void gload16(u16* lds, const u16* g) {
    __builtin_amdgcn_global_load_lds(
        (const __attribute__((address_space(1))) unsigned*)g,
        (__attribute__((address_space(3))) unsigned*)lds,
        16, 0, 0);
}

#define CFENCE asm volatile("" ::: "memory")

// ---------------- elementwise f32 -> bf16 cast (vectorized) ----------------
__global__ void cast_kernel(const float* __restrict__ in, u16* __restrict__ out, int n4) {
    int stride = gridDim.x * blockDim.x;
    for (int i = blockIdx.x * blockDim.x + threadIdx.x; i < n4; i += stride) {
        float4 v = ((const float4*)in)[i];
        short4v o;
        o[0] = (short)f2bf(v.x);
        o[1] = (short)f2bf(v.y);
        o[2] = (short)f2bf(v.z);
        o[3] = (short)f2bf(v.w);
        ((short4v*)out)[i] = o;
    }
}

// ------------- emb [32000][4096] f32 -> Et [4096][32000] bf16 --------------
__global__ void transpose_cast(const float* __restrict__ E, u16* __restrict__ Et) {
    __shared__ u16 t[32][34];
    int bx = blockIdx.x, by = blockIdx.y;
    int x = threadIdx.x, y = threadIdx.y;
    long long c = (long long)bx * 32 + x;
    long long r0 = (long long)by * 32;
#pragma unroll
    for (int i = y; i < 32; i += 8)
        t[x][i] = f2bf(E[(r0 + i) * 4096 + c]);
    __syncthreads();
    int v = by * 32 + x;
#pragma unroll
    for (int i = y; i < 32; i += 8)
        Et[(long long)(bx * 32 + i) * 32000 + v] = t[i][x];
}

// ---------------- row sums of P (bf16) -> l (f32), deterministic -----------
__global__ void rowsum_kernel(const u16* __restrict__ P, float* __restrict__ l, int V) {
    long long base = (long long)blockIdx.x * V;
    const short8* p8 = (const short8*)(P + base);
    int n8 = V >> 3;
    float s = 0.f;
    for (int c = threadIdx.x; c < n8; c += blockDim.x) {
        short8 v = p8[c];
#pragma unroll
        for (int j = 0; j < 8; ++j) s += bf2f((u16)v[j]);
    }
#pragma unroll
    for (int off = 32; off > 0; off >>= 1) s += __shfl_down(s, off, 64);
    __shared__ float red[4];
    if ((threadIdx.x & 63) == 0) red[threadIdx.x >> 6] = s;
    __syncthreads();
    if (threadIdx.x == 0) l[blockIdx.x] = red[0] + red[1] + red[2] + red[3];
}

// =================== 256x256 8-phase NT GEMM (T1-T5) =======================
// C[M][N] = A[M][K] * B[N][K]^T. 8 waves (2Mx4N), BK=64, 2 K-tile dbuf.
// LDS [buf][op][half][128][64] bf16 = 128 KiB.
// bf0 (Bh0 frags) kept live P1->P4: no re-read; P2/P4 have zero ds_reads.
// Barriers: P1 x2, P2 x0, P3 x2, P4 x2 (hazard audit in round-4 notes).

__device__ __forceinline__ void stageA(u16* ldsh, const u16* Abase, int h, int t,
                                       int K, int w, int lane) {
#pragma unroll
    for (int i = 0; i < 2; ++i) {
        int r = w * 16 + i * 8 + (lane >> 3);
        int gc = (lane & 7) ^ ((r >> 1) & 7);
        int grow = ((r >> 6) << 7) + (h << 6) + (r & 63);
        gload16(ldsh + (w * 16 + i * 8) * 64,
                Abase + (long long)grow * K + t * 64 + gc * 8);
    }
}
__device__ __forceinline__ void stageB(u16* ldsh, const u16* Bbase, int h, int t,
                                       int K, int w, int lane) {
#pragma unroll
    for (int i = 0; i < 2; ++i) {
        int r = w * 16 + i * 8 + (lane >> 3);
        int gc = (lane & 7) ^ ((r >> 1) & 7);
        int grow = ((r >> 5) << 6) + (h << 5) + (r & 31);
        gload16(ldsh + (w * 16 + i * 8) * 64,
                Bbase + (long long)grow * K + t * 64 + gc * 8);
    }
}

template <int MH>
__device__ __forceinline__ void loadA(short8 af[4][2], const u16 (*lA)[128][64],
                                      int wm, int fRow, int fC) {
#pragma unroll
    for (int m = 0; m < 4; ++m)
#pragma unroll
        for (int kk = 0; kk < 2; ++kk) {
            int R = wm * 64 + m * 16 + fRow;
            int slot = (kk * 4 + fC) ^ ((R >> 1) & 7);
            af[m][kk] = *(const short8*)&lA[MH][R][slot * 8];
        }
}
template <int NH>
__device__ __forceinline__ void loadB(short8 bf[2][2], const u16 (*lB)[128][64],
                                      int wn, int fRow, int fC) {
#pragma unroll
    for (int n = 0; n < 2; ++n)
#pragma unroll
        for (int kk = 0; kk < 2; ++kk) {
            int R = wn * 32 + n * 16 + fRow;
            int slot = (kk * 4 + fC) ^ ((R >> 1) & 7);
            bf[n][kk] = *(const short8*)&lB[NH][R][slot * 8];
        }
}
template <int MH, int NH>
__device__ __forceinline__ void mfma16(floatx4 acc[8][4], short8 af[4][2],
                                       short8 bf[2][2]) {
#pragma unroll
    for (int m = 0; m < 4; ++m)
#pragma unroll
        for (int n = 0; n < 2; ++n)
#pragma unroll
            for (int kk = 0; kk < 2; ++kk)
                acc[MH * 4 + m][NH * 2 + n] = __builtin_amdgcn_mfma_f32_16x16x32_bf16(
                    af[m][kk], bf[n][kk], acc[MH * 4 + m][NH * 2 + n], 0, 0, 0);
}

// EP=0: store exp(C + bias[col]) as bf16.  EP=1: store C/rowsum[row] as f32.
template <int EP>
__global__ __launch_bounds__(512, 2)
void gemm8p(const u16* __restrict__ A, const u16* __restrict__ B,
            int M, int N, int K,
            const float* __restrict__ bias, u16* __restrict__ Pout,
            const float* __restrict__ rsum, float* __restrict__ Cout) {
    __shared__ u16 lds[2][2][2][128][64];
    const int tid = threadIdx.x;
    const int w = tid >> 6, lane = tid & 63;
    const int wm = w >> 2, wn = w & 3;
    const int fRow = lane & 15, fC = lane >> 4;

    // T1 tile maps. grid==256 (GEMM2): 4tm x 8tn per XCD (per-XCD stream
    // 196 MB vs 294). Else: chunked XCD swizzle, tm-fastest.
    int tm, tn;
    const int nTm = M >> 8;
    if (gridDim.x == 256) {
        const int x = blockIdx.x & 7, wgx = blockIdx.x >> 3;
        tm = (x & 3) * 4 + (wgx & 3);
        tn = (x >> 2) * 8 + (wgx >> 2);
    } else {
        const int q = gridDim.x >> 3;
        const int wg = (blockIdx.x & 7) * q + (blockIdx.x >> 3);
        tm = wg % nTm;
        tn = wg / nTm;
    }

    const u16* Abase = A + (long long)tm * 256 * K;
    const u16* Bbase = B + (long long)tn * 256 * K;
    const int NT = K >> 6;

    floatx4 acc[8][4] = {};
    short8 af[4][2], bf0[2][2], bf1[2][2];

    // ---- prologue: tile0 (4 halves) + tile1 {Ah0,Bh1,Ah1} -> vmcnt(6) ----
    stageA(&lds[0][0][0][0][0], Abase, 0, 0, K, w, lane);
    stageB(&lds[0][1][0][0][0], Bbase, 0, 0, K, w, lane);
    stageB(&lds[0][1][1][0][0], Bbase, 1, 0, K, w, lane);
    stageA(&lds[0][0][1][0][0], Abase, 1, 0, K, w, lane);
    if (NT > 1) {
        stageA(&lds[1][0][0][0][0], Abase, 0, 1, K, w, lane);
        stageB(&lds[1][1][1][0][0], Bbase, 1, 1, K, w, lane);
        stageA(&lds[1][0][1][0][0], Abase, 1, 1, K, w, lane);
        asm volatile("s_waitcnt vmcnt(6)" ::: "memory");
    } else {
        asm volatile("s_waitcnt vmcnt(0)" ::: "memory");
    }
    __builtin_amdgcn_s_barrier();
    CFENCE;

    for (int t = 0; t < NT; ++t) {
        const int d = t & 1;
        const u16(*lA)[128][64] = lds[d][0];
        const u16(*lB)[128][64] = lds[d][1];

        // ---- P1: read A0,B0,B1; stage Bh0(t+1); MFMA (0,0) ----
        loadA<0>(af, lA, wm, fRow, fC);
        loadB<0>(bf0, lB, wn, fRow, fC);
        loadB<1>(bf1, lB, wn, fRow, fC);
        if (t + 1 < NT) stageB(&lds[d ^ 1][1][0][0][0], Bbase, 0, t + 1, K, w, lane);
        asm volatile("s_waitcnt lgkmcnt(8)" ::: "memory");
        __builtin_amdgcn_s_barrier();
        asm volatile("s_waitcnt lgkmcnt(0)" ::: "memory");
        __builtin_amdgcn_s_setprio(1);
        mfma16<0, 0>(acc, af, bf0);
        __builtin_amdgcn_s_setprio(0);
        __builtin_amdgcn_s_barrier();
        CFENCE;

        // ---- P2: no reads, no barriers; stage Ah0(t+2); MFMA (0,1) ----
        if (t + 2 < NT) stageA(&lds[d][0][0][0][0], Abase, 0, t + 2, K, w, lane);
        __builtin_amdgcn_s_setprio(1);
        mfma16<0, 1>(acc, af, bf1);
        __builtin_amdgcn_s_setprio(0);
        CFENCE;

        // ---- P3: read A1; stage Bh1(t+2); MFMA (1,1) ----
        loadA<1>(af, lA, wm, fRow, fC);
        if (t + 2 < NT) stageB(&lds[d][1][1][0][0], Bbase, 1, t + 2, K, w, lane);
        asm volatile("s_waitcnt lgkmcnt(4)" ::: "memory");
        __builtin_amdgcn_s_barrier();
        asm volatile("s_waitcnt lgkmcnt(0)" ::: "memory");
        __builtin_amdgcn_s_setprio(1);
        mfma16<1, 1>(acc, af, bf1);
        __builtin_amdgcn_s_setprio(0);
        __builtin_amdgcn_s_barrier();
        CFENCE;

        // ---- P4: no reads; stage Ah1(t+2); counted vmcnt; MFMA (1,0) ----
        if (t + 2 < NT) {
            stageA(&lds[d][0][1][0][0], Abase, 1, t + 2, K, w, lane);
            asm volatile("s_waitcnt vmcnt(6)" ::: "memory");
        } else if (t + 1 < NT) {
            asm volatile("s_waitcnt vmcnt(0)" ::: "memory");
        }
        __builtin_amdgcn_s_barrier();
        __builtin_amdgcn_s_setprio(1);
        mfma16<1, 0>(acc, af, bf0);
        __builtin_amdgcn_s_setprio(0);
        __builtin_amdgcn_s_barrier();
        CFENCE;
    }

    // ---- epilogue: C/D layout col=lane&15, row=(lane>>4)*4+reg ----
    const int rBase = tm * 256 + wm * 128;
    const int cBase = tn * 256 + wn * 64;
    const int rOff = (lane >> 4) * 4;
    const int cOff = lane & 15;
#pragma unroll
    for (int m = 0; m < 8; ++m) {
#pragma unroll
        for (int n = 0; n < 4; ++n) {
            const int col = cBase + n * 16 + cOff;
            if (EP == 0) {
                float bv = bias[col];
#pragma unroll
                for (int r = 0; r < 4; ++r) {
                    int row = rBase + m * 16 + rOff + r;
                    Pout[(long long)row * N + col] = f2bf(__expf(acc[m][n][r] + bv));
                }
            } else {
#pragma unroll
                for (int r = 0; r < 4; ++r) {
                    int row = rBase + m * 16 + rOff + r;
                    Cout[(long long)row * N + col] = acc[m][n][r] * (1.0f / rsum[row]);
                }
            }
        }
    }
}

extern "C" void kernel_launch(void* const* d_in, const int* in_sizes, int n_in,
                              void* d_out, int out_size, void* d_ws, size_t ws_size,
                              hipStream_t stream) {
    const float* x = (const float*)d_in[0];   // [2,2048,1024]
    const float* W = (const float*)d_in[1];   // [32000,1024]
    const float* b = (const float*)d_in[2];   // [32000]
    const float* E = (const float*)d_in[3];   // [32000,4096]
    float* out = (float*)d_out;               // [2,2048,4096]

    const int M = 4096, K1 = 1024, V = 32000, N2 = 4096;

    char* ws = (char*)d_ws;
    size_t off = 0;
    u16* xb = (u16*)(ws + off); off += (size_t)M * K1 * 2;
    u16* Wb = (u16*)(ws + off); off += (size_t)V * K1 * 2;
    u16* Et = (u16*)(ws + off); off += (size_t)N2 * V * 2;
    u16* P  = (u16*)(ws + off); off += (size_t)M * V * 2;
    float* l = (float*)(ws + off); off += (size_t)M * 4;

    cast_kernel<<<2048, 256, 0, stream>>>(x, xb, M * K1 / 4);
    cast_kernel<<<2048, 256, 0, stream>>>(W, Wb, V * K1 / 4);
    transpose_cast<<<dim3(N2 / 32, V / 32), dim3(32, 8), 0, stream>>>(E, Et);
    // GEMM1: [4096 x 32000 x 1024] -> P = exp(x@W^T + b), bf16
    gemm8p<0><<<(M / 256) * (V / 256), 512, 0, stream>>>(xb, Wb, M, V, K1, b, P, nullptr, nullptr);
    rowsum_kernel<<<M, 256, 0, stream>>>(P, l, V);
    // GEMM2: [4096 x 4096 x 32000] -> out = (P/l) @ Et^T, f32
    gemm8p<1><<<(M / 256) * (N2 / 256), 512, 0, stream>>>(P, Et, M, N2, V, nullptr, nullptr, l, out);
}

// Round 5
// 1388.955 us; speedup vs baseline: 1.8324x; 1.0197x over previous
//
#include <hip/hip_runtime.h>
#include <cstdint>

typedef unsigned short u16;
typedef __attribute__((ext_vector_type(8))) short short8;
typedef __attribute__((ext_vector_type(4))) short short4v;
typedef __attribute__((ext_vector_type(4))) float floatx4;

__device__ __forceinline__ u16 f2bf(float f) {
    unsigned u = __float_as_uint(f);
    return (u16)((u + 0x7FFFu + ((u >> 16) & 1u)) >> 16);  // RNE
}
__device__ __forceinline__ float bf2f(u16 h) {
    return __uint_as_float(((unsigned)h) << 16);
}

__device__ __forceinline__ void gload16(u16* lds, const u16* g) {
    __builtin_amdgcn_global_load_lds(
        (const __attribute__((address_space(1))) unsigned*)g,
        (__attribute__((address_space(3))) unsigned*)lds,
        16, 0, 0);
}

#define CFENCE asm volatile("" ::: "memory")
#define MFMA_BF16 __builtin_amdgcn_mfma_f32_16x16x32_bf16

// ---------------- elementwise f32 -> bf16 cast (vectorized) ----------------
__global__ void cast_kernel(const float* __restrict__ in, u16* __restrict__ out, int n4) {
    int stride = gridDim.x * blockDim.x;
    for (int i = blockIdx.x * blockDim.x + threadIdx.x; i < n4; i += stride) {
        float4 v = ((const float4*)in)[i];
        short4v o;
        o[0] = (short)f2bf(v.x);
        o[1] = (short)f2bf(v.y);
        o[2] = (short)f2bf(v.z);
        o[3] = (short)f2bf(v.w);
        ((short4v*)out)[i] = o;
    }
}

// ------------- emb [32000][4096] f32 -> Et [4096][32000] bf16 --------------
__global__ void transpose_cast(const float* __restrict__ E, u16* __restrict__ Et) {
    __shared__ u16 t[32][34];
    int bx = blockIdx.x, by = blockIdx.y;
    int x = threadIdx.x, y = threadIdx.y;
    long long c = (long long)bx * 32 + x;
    long long r0 = (long long)by * 32;
#pragma unroll
    for (int i = y; i < 32; i += 8)
        t[x][i] = f2bf(E[(r0 + i) * 4096 + c]);
    __syncthreads();
    int v = by * 32 + x;
#pragma unroll
    for (int i = y; i < 32; i += 8)
        Et[(long long)(bx * 32 + i) * 32000 + v] = t[i][x];
}

// ---------------- row sums of P (bf16) -> l (f32), deterministic -----------
__global__ void rowsum_kernel(const u16* __restrict__ P, float* __restrict__ l, int V) {
    long long base = (long long)blockIdx.x * V;
    const short8* p8 = (const short8*)(P + base);
    int n8 = V >> 3;
    float s = 0.f;
    for (int c = threadIdx.x; c < n8; c += blockDim.x) {
        short8 v = p8[c];
#pragma unroll
        for (int j = 0; j < 8; ++j) s += bf2f((u16)v[j]);
    }
#pragma unroll
    for (int off = 32; off > 0; off >>= 1) s += __shfl_down(s, off, 64);
    __shared__ float red[4];
    if ((threadIdx.x & 63) == 0) red[threadIdx.x >> 6] = s;
    __syncthreads();
    if (threadIdx.x == 0) l[blockIdx.x] = red[0] + red[1] + red[2] + red[3];
}

// ============ 256x256 NT GEMM, 2-barrier deep-pipelined schedule ===========
// C[M][N] = A[M][K] * B[N][K]^T. 8 waves (2Mx4N), BK=64, 2 K-tile dbuf.
// LDS [buf][op][half][128][64] bf16 = 128 KiB. Chunk-XOR swizzle (0 conflicts).
//
// Per-tile schedule (hazard audit):
//  P1: read bf0(t) [4]; stage Bh0(t+1); LGKM(0)  <- master guard: forces ALL
//      outstanding ds_reads (incl. bf1(t)/af0(t) prefetched last P4) complete
//      before B1, so P2's stages into [d][0][0]/[d][1][1] are safe (H1,H2).
//      MFMA Q(0,0); B1.
//  P2: stage Ah0(t+2),Bh1(t+2); MFMA Q(0,1) interleaved with af1(t) reads
//      (af[m] reloaded right after its last Q(0,1) use - zero extra VGPR).
//  P3: MFMA Q(1,1)  (compiler dataflow-waits af1; completion before B2 => H3).
//  P4: vmcnt(4) = keep {Ah0(t+2),Bh1(t+2)} -> retires through Bh0(t+1):
//      tile t+1 FULLY resident (Ah1(t+1) staged P4(t-1) is older). B2.
//      stage Ah1(t+2) (after B2: H3). MFMA Q(1,0) interleaved with
//      bf1(t+1) + af0(t+1) reads from buf d^1 (resident per vmcnt(4)+B2).
// Barrier sequence identical for all waves (B1,B2 alternating) -> matched.
// EP=0: store exp(C + bias[col]) bf16.  EP=1: store C/rowsum[row] f32.

__device__ __forceinline__ void stageA(u16* ldsh, const u16* Abase, int h, int t,
                                       int K, int w, int lane) {
#pragma unroll
    for (int i = 0; i < 2; ++i) {
        int r = w * 16 + i * 8 + (lane >> 3);
        int gc = (lane & 7) ^ ((r >> 1) & 7);
        int grow = ((r >> 6) << 7) + (h << 6) + (r & 63);
        gload16(ldsh + (w * 16 + i * 8) * 64,
                Abase + (long long)grow * K + t * 64 + gc * 8);
    }
}
__device__ __forceinline__ void stageB(u16* ldsh, const u16* Bbase, int h, int t,
                                       int K, int w, int lane) {
#pragma unroll
    for (int i = 0; i < 2; ++i) {
        int r = w * 16 + i * 8 + (lane >> 3);
        int gc = (lane & 7) ^ ((r >> 1) & 7);
        int grow = ((r >> 5) << 6) + (h << 5) + (r & 31);
        gload16(ldsh + (w * 16 + i * 8) * 64,
                Bbase + (long long)grow * K + t * 64 + gc * 8);
    }
}

__device__ __forceinline__ short8 ldsRead(const u16 (*lH)[64], int R, int kk, int fC) {
    int slot = (kk * 4 + fC) ^ ((R >> 1) & 7);
    return *(const short8*)&lH[R][slot * 8];
}

template <int EP>
__global__ __launch_bounds__(512, 2)
void gemm8p(const u16* __restrict__ A, const u16* __restrict__ B,
            int M, int N, int K,
            const float* __restrict__ bias, u16* __restrict__ Pout,
            const float* __restrict__ rsum, float* __restrict__ Cout) {
    __shared__ u16 lds[2][2][2][128][64];
    const int tid = threadIdx.x;
    const int w = tid >> 6, lane = tid & 63;
    const int wm = w >> 2, wn = w & 3;
    const int fRow = lane & 15, fC = lane >> 4;

    int tm, tn;
    const int nTm = M >> 8;
    if (gridDim.x == 256) {            // GEMM2: 4tm x 8tn per XCD
        const int x = blockIdx.x & 7, wgx = blockIdx.x >> 3;
        tm = (x & 3) * 4 + (wgx & 3);
        tn = (x >> 2) * 8 + (wgx >> 2);
    } else {                           // chunked XCD swizzle, tm-fastest
        const int q = gridDim.x >> 3;
        const int wg = (blockIdx.x & 7) * q + (blockIdx.x >> 3);
        tm = wg % nTm;
        tn = wg / nTm;
    }

    const u16* Abase = A + (long long)tm * 256 * K;
    const u16* Bbase = B + (long long)tn * 256 * K;
    const int NT = K >> 6;

    floatx4 acc[8][4] = {};
    short8 af[4][2], bf0[2][2], bf1[2][2];

    // ---- prologue: tile0 {A0,B0,B1,A1} + tile1 {Ah0,Bh1,Ah1}; vmcnt(6)
    //      leaves exactly tile1's 3 halves outstanding (FIFO audit above) ----
    stageA(&lds[0][0][0][0][0], Abase, 0, 0, K, w, lane);
    stageB(&lds[0][1][0][0][0], Bbase, 0, 0, K, w, lane);
    stageB(&lds[0][1][1][0][0], Bbase, 1, 0, K, w, lane);
    stageA(&lds[0][0][1][0][0], Abase, 1, 0, K, w, lane);
    if (NT > 1) {
        stageA(&lds[1][0][0][0][0], Abase, 0, 1, K, w, lane);
        stageB(&lds[1][1][1][0][0], Bbase, 1, 1, K, w, lane);
        stageA(&lds[1][0][1][0][0], Abase, 1, 1, K, w, lane);
        asm volatile("s_waitcnt vmcnt(6)" ::: "memory");
    } else {
        asm volatile("s_waitcnt vmcnt(0)" ::: "memory");
    }
    __builtin_amdgcn_s_barrier();
    CFENCE;
    // preload af0(0), bf1(0) (steady state expects them in regs at P1)
#pragma unroll
    for (int m = 0; m < 4; ++m)
#pragma unroll
        for (int kk = 0; kk < 2; ++kk)
            af[m][kk] = ldsRead(&lds[0][0][0][0], wm * 64 + m * 16 + fRow, kk, fC);
#pragma unroll
    for (int n = 0; n < 2; ++n)
#pragma unroll
        for (int kk = 0; kk < 2; ++kk)
            bf1[n][kk] = ldsRead(&lds[0][1][1][0], wn * 32 + n * 16 + fRow, kk, fC);

    for (int t = 0; t < NT; ++t) {
        const int d = t & 1;

        // ---------------- P1 ----------------
#pragma unroll
        for (int n = 0; n < 2; ++n)
#pragma unroll
            for (int kk = 0; kk < 2; ++kk)
                bf0[n][kk] = ldsRead(&lds[d][1][0][0], wn * 32 + n * 16 + fRow, kk, fC);
        if (t + 1 < NT) stageB(&lds[d ^ 1][1][0][0][0], Bbase, 0, t + 1, K, w, lane);
        asm volatile("s_waitcnt lgkmcnt(0)" ::: "memory");
        __builtin_amdgcn_sched_barrier(0);
        __builtin_amdgcn_s_setprio(1);
#pragma unroll
        for (int m = 0; m < 4; ++m)
#pragma unroll
            for (int n = 0; n < 2; ++n)
#pragma unroll
                for (int kk = 0; kk < 2; ++kk)
                    acc[m][n] = MFMA_BF16(af[m][kk], bf0[n][kk], acc[m][n], 0, 0, 0);
        __builtin_amdgcn_s_setprio(0);
        __builtin_amdgcn_s_barrier();   // B1
        CFENCE;

        // ---------------- P2 ----------------
        if (t + 2 < NT) {
            stageA(&lds[d][0][0][0][0], Abase, 0, t + 2, K, w, lane);
            stageB(&lds[d][1][1][0][0], Bbase, 1, t + 2, K, w, lane);
        }
        __builtin_amdgcn_s_setprio(1);
#pragma unroll
        for (int m = 0; m < 4; ++m) {
#pragma unroll
            for (int n = 0; n < 2; ++n)
#pragma unroll
                for (int kk = 0; kk < 2; ++kk)
                    acc[m][2 + n] = MFMA_BF16(af[m][kk], bf1[n][kk], acc[m][2 + n], 0, 0, 0);
            // af[m] dead for Q(0,1): reload with A-half1(t) under the cluster
#pragma unroll
            for (int kk = 0; kk < 2; ++kk)
                af[m][kk] = ldsRead(&lds[d][0][1][0], wm * 64 + m * 16 + fRow, kk, fC);
        }
        __builtin_amdgcn_s_setprio(0);

        // ---------------- P3 ----------------
        __builtin_amdgcn_s_setprio(1);
#pragma unroll
        for (int m = 0; m < 4; ++m)
#pragma unroll
            for (int n = 0; n < 2; ++n)
#pragma unroll
                for (int kk = 0; kk < 2; ++kk)
                    acc[4 + m][2 + n] = MFMA_BF16(af[m][kk], bf1[n][kk], acc[4 + m][2 + n], 0, 0, 0);
        __builtin_amdgcn_s_setprio(0);

        // ---------------- P4 ----------------
        if (t + 2 < NT) {
            asm volatile("s_waitcnt vmcnt(4)" ::: "memory");
        } else if (t + 1 < NT) {
            asm volatile("s_waitcnt vmcnt(0)" ::: "memory");
        }
        __builtin_amdgcn_s_barrier();   // B2
        CFENCE;
        if (t + 2 < NT) stageA(&lds[d][0][1][0][0], Abase, 1, t + 2, K, w, lane);
        if (t + 1 < NT) {
            // prefetch bf1(t+1) at cluster start (bf1 dead after P3)
#pragma unroll
            for (int n = 0; n < 2; ++n)
#pragma unroll
                for (int kk = 0; kk < 2; ++kk)
                    bf1[n][kk] = ldsRead(&lds[d ^ 1][1][1][0], wn * 32 + n * 16 + fRow, kk, fC);
            __builtin_amdgcn_s_setprio(1);
#pragma unroll
            for (int m = 0; m < 4; ++m) {
#pragma unroll
                for (int n = 0; n < 2; ++n)
#pragma unroll
                    for (int kk = 0; kk < 2; ++kk)
                        acc[4 + m][n] = MFMA_BF16(af[m][kk], bf0[n][kk], acc[4 + m][n], 0, 0, 0);
                // af[m] dead: reload with A-half0(t+1) under the cluster
#pragma unroll
                for (int kk = 0; kk < 2; ++kk)
                    af[m][kk] = ldsRead(&lds[d ^ 1][0][0][0], wm * 64 + m * 16 + fRow, kk, fC);
            }
            __builtin_amdgcn_s_setprio(0);
        } else {
            __builtin_amdgcn_s_setprio(1);
#pragma unroll
            for (int m = 0; m < 4; ++m)
#pragma unroll
                for (int n = 0; n < 2; ++n)
#pragma unroll
                    for (int kk = 0; kk < 2; ++kk)
                        acc[4 + m][n] = MFMA_BF16(af[m][kk], bf0[n][kk], acc[4 + m][n], 0, 0, 0);
            __builtin_amdgcn_s_setprio(0);
        }
        CFENCE;
    }

    // ---- epilogue: C/D layout col=lane&15, row=(lane>>4)*4+reg ----
    const int rBase = tm * 256 + wm * 128;
    const int cBase = tn * 256 + wn * 64;
    const int rOff = (lane >> 4) * 4;
    const int cOff = lane & 15;
#pragma unroll
    for (int m = 0; m < 8; ++m) {
#pragma unroll
        for (int n = 0; n < 4; ++n) {
            const int col = cBase + n * 16 + cOff;
            if (EP == 0) {
                float bv = bias[col];
#pragma unroll
                for (int r = 0; r < 4; ++r) {
                    int row = rBase + m * 16 + rOff + r;
                    Pout[(long long)row * N + col] = f2bf(__expf(acc[m][n][r] + bv));
                }
            } else {
#pragma unroll
                for (int r = 0; r < 4; ++r) {
                    int row = rBase + m * 16 + rOff + r;
                    Cout[(long long)row * N + col] = acc[m][n][r] * (1.0f / rsum[row]);
                }
            }
        }
    }
}

extern "C" void kernel_launch(void* const* d_in, const int* in_sizes, int n_in,
                              void* d_out, int out_size, void* d_ws, size_t ws_size,
                              hipStream_t stream) {
    const float* x = (const float*)d_in[0];   // [2,2048,1024]
    const float* W = (const float*)d_in[1];   // [32000,1024]
    const float* b = (const float*)d_in[2];   // [32000]
    const float* E = (const float*)d_in[3];   // [32000,4096]
    float* out = (float*)d_out;               // [2,2048,4096]

    const int M = 4096, K1 = 1024, V = 32000, N2 = 4096;

    char* ws = (char*)d_ws;
    size_t off = 0;
    u16* xb = (u16*)(ws + off); off += (size_t)M * K1 * 2;
    u16* Wb = (u16*)(ws + off); off += (size_t)V * K1 * 2;
    u16* Et = (u16*)(ws + off); off += (size_t)N2 * V * 2;
    u16* P  = (u16*)(ws + off); off += (size_t)M * V * 2;
    float* l = (float*)(ws + off); off += (size_t)M * 4;

    cast_kernel<<<2048, 256, 0, stream>>>(x, xb, M * K1 / 4);
    cast_kernel<<<2048, 256, 0, stream>>>(W, Wb, V * K1 / 4);
    transpose_cast<<<dim3(N2 / 32, V / 32), dim3(32, 8), 0, stream>>>(E, Et);
    // GEMM1: [4096 x 32000 x 1024] -> P = exp(x@W^T + b), bf16
    gemm8p<0><<<(M / 256) * (V / 256), 512, 0, stream>>>(xb, Wb, M, V, K1, b, P, nullptr, nullptr);
    rowsum_kernel<<<M, 256, 0, stream>>>(P, l, V);
    // GEMM2: [4096 x 4096 x 32000] -> out = (P/l) @ Et^T, f32
    gemm8p<1><<<(M / 256) * (N2 / 256), 512, 0, stream>>>(P, Et, M, N2, V, nullptr, nullptr, l, out);
}